// Round 3
// baseline (211.745 us; speedup 1.0000x reference)
//
#include <hip/hip_runtime.h>

// ---------------------------------------------------------------------------
// MultiheadSelfAttention (row-local head-mixing variant), MI355X / gfx950.
// Round 11: faithful 256x256 8-phase template port for GEMM1 (attempt #2).
// Fixes vs R9: 16x16x32 MFMA (2-way LDS conflicts = free, vs 4-way for 32x32),
// half-tile (2-load) staging EVERY phase, uniform vmcnt(4) at phases 4/8 only,
// raw s_barrier + post-barrier lgkmcnt(0), setprio around 16-MFMA clusters,
// bijective XCD swizzle.  GEMM2 / attn / cvt identical to round 8.
// ---------------------------------------------------------------------------

typedef __bf16 bf16x8 __attribute__((ext_vector_type(8)));
typedef float  f32x16 __attribute__((ext_vector_type(16)));
typedef float  f32x4  __attribute__((ext_vector_type(4)));

typedef __attribute__((address_space(3))) void       lds_void;
typedef const __attribute__((address_space(1))) void gbl_void;

__device__ __forceinline__ unsigned short f2b(float f) {
    unsigned int u = __builtin_bit_cast(unsigned int, f);
    return (unsigned short)((u + 0x7FFFu + ((u >> 16) & 1u)) >> 16);  // RNE
}
__device__ __forceinline__ unsigned int pack2(float a, float b) {
    return (unsigned int)f2b(a) | ((unsigned int)f2b(b) << 16);
}
__device__ __forceinline__ void unpack8(uint4 u, float* f) {
    unsigned int w[4] = {u.x, u.y, u.z, u.w};
#pragma unroll
    for (int a = 0; a < 4; ++a) {
        union { unsigned int i; float f; } lo, hi;
        lo.i = w[a] << 16;
        hi.i = w[a] & 0xFFFF0000u;
        f[a * 2]     = lo.f;
        f[a * 2 + 1] = hi.f;
    }
}

// ------------------------- fused fp32 -> bf16 cast -------------------------
__global__ __launch_bounds__(256) void cvt_all(const float* __restrict__ x,
                                               const float* __restrict__ wqkv,
                                               const float* __restrict__ wproj,
                                               unsigned short* __restrict__ xb,
                                               unsigned short* __restrict__ wqkvb,
                                               unsigned short* __restrict__ wprojb) {
    int i = blockIdx.x * 256 + threadIdx.x;
    const float* src;
    unsigned short* dst;
    if (i < 2097152)      { src = x;     dst = xb;                   }
    else if (i < 2883584) { src = wqkv;  dst = wqkvb;  i -= 2097152; }
    else                  { src = wproj; dst = wprojb; i -= 2883584; }
    float4 f = reinterpret_cast<const float4*>(src)[i];
    ushort4 u;
    u.x = f2b(f.x); u.y = f2b(f.y); u.z = f2b(f.z); u.w = f2b(f.w);
    reinterpret_cast<ushort4*>(dst)[i] = u;
}

__device__ __forceinline__ void store_c(float* C, long idx, float v)          { C[idx] = v; }
__device__ __forceinline__ void store_c(unsigned short* C, long idx, float v) { C[idx] = f2b(v); }

// ---------------- 256x256 8-phase bf16 NT GEMM (Round 11) ------------------
// C[m,n] = sum_k A[m,k]*B[n,k].  A: MxK rm, B: NxK rm (bf16 bits as ushort).
// 512 threads = 8 waves (2M x 4N); wave tile 128x64 = acc[8][4] of 16x16.
// LDS: 2 buffers x (A 256x64 + B 256x64) = 128 KiB.  Row = 8 chunks of 16B,
// chunk c of row r at slot c^(r&7); linear dest for global_load_lds with
// inverse-swizzled global source; 16x16 fragments read 16 rows/lane-group ->
// 2-way residual conflict (free, m136).
// Per K-tile, 4 phases (C-quadrants q00,q01,q11,q10); af reused (m0-3 then
// m4-7), b01/b23 cached; reads/phase = 12/4/8/0.  One half-tile (2 loads)
// staged every phase; vmcnt(4) at phases 4 and 8 only (never 0 in loop).
#define BAR   __builtin_amdgcn_s_barrier()
#define LGKM0 asm volatile("s_waitcnt lgkmcnt(0)" ::: "memory")
#define LGKM8 asm volatile("s_waitcnt lgkmcnt(8)" ::: "memory")
#define VM4   asm volatile("s_waitcnt vmcnt(4)" ::: "memory")

template <typename CT>
__global__ __launch_bounds__(512, 2) void gemm256p(const unsigned short* __restrict__ A,
                                                   const unsigned short* __restrict__ B,
                                                   CT* __restrict__ C,
                                                   int M, int N, int K, int NBX) {
    __shared__ __align__(16) unsigned short sA[2][16384];  // 2 x 32 KiB
    __shared__ __align__(16) unsigned short sB[2][16384];  // 2 x 32 KiB

    const int tid  = threadIdx.x;
    const int lane = tid & 63;
    const int wave = tid >> 6;
    const int wm   = wave >> 2;            // 0..1  (M half)
    const int wn   = wave & 3;             // 0..3  (N quarter)

    // bijective XCD swizzle (gridDim.x % 8 == 0)
    const int nwg = gridDim.x;
    const int cpx = nwg >> 3;
    const int swz = (blockIdx.x & 7) * cpx + (blockIdx.x >> 3);
    const long bm = swz / NBX;
    const long bn = swz % NBX;

    const unsigned short* Ab = A + bm * 256 * (long)K;
    const unsigned short* Bb = B + bn * 256 * (long)K;

    f32x4 acc[8][4] = {};

    // stage one half-tile (128 rows x 64 k): 2 x global_load_lds per thread.
    // LDS dest linear; global source chunk inverse-swizzled (slot c^(r&7)).
    auto stage = [&](const unsigned short* __restrict__ G, unsigned short* L,
                     int tile, int half) {
        const int r = tid >> 3;                            // 0..63
        const int c = ((tid & 7) ^ (r & 7)) << 3;
        const unsigned short* g = G + (long)(half * 128 + r) * K + (long)tile * 64 + c;
        unsigned short* l = L + half * 8192 + wave * 512;
#pragma unroll
        for (int j = 0; j < 2; ++j)
            __builtin_amdgcn_global_load_lds((gbl_void*)(g + (long)j * 64 * K),
                                             (lds_void*)(l + j * 4096), 16, 0, 0);
    };

    // prologue: tile0 full + B(tile1); wait tile0 (4 = B(1) stays in flight)
    stage(Bb, &sB[0][0], 0, 0); stage(Bb, &sB[0][0], 0, 1);
    stage(Ab, &sA[0][0], 0, 0); stage(Ab, &sA[0][0], 0, 1);
    stage(Bb, &sB[1][0], 1, 0); stage(Bb, &sB[1][0], 1, 1);
    VM4;
    BAR;

    const int fr = lane & 15;              // fragment row (A) / col (B)
    const int fk = lane >> 4;              // k-chunk 0..3
    const int sx = lane & 7;               // swizzle XOR (row&7 == lane&7 for 16-tiles)

    bf16x8 af[4][2], b01[2][2], b23[2][2];

    auto read_a4 = [&](int q, int mbase) {
#pragma unroll
        for (int mt = 0; mt < 4; ++mt) {
            const int row = wm * 128 + (mbase + mt) * 16 + fr;
#pragma unroll
            for (int h = 0; h < 2; ++h)
                af[mt][h] = *reinterpret_cast<const bf16x8*>(
                    &sA[q][row * 64 + (((h * 4 + fk) ^ sx) << 3)]);
        }
    };
    auto read_b2 = [&](int q, int nbase, bf16x8 (&bf)[2][2]) {
#pragma unroll
        for (int nt = 0; nt < 2; ++nt) {
            const int row = wn * 64 + (nbase + nt) * 16 + fr;
#pragma unroll
            for (int h = 0; h < 2; ++h)
                bf[nt][h] = *reinterpret_cast<const bf16x8*>(
                    &sB[q][row * 64 + (((h * 4 + fk) ^ sx) << 3)]);
        }
    };
    auto mmq = [&](int mbase, int nbase, bf16x8 (&bf)[2][2]) {
        __builtin_amdgcn_s_setprio(1);
#pragma unroll
        for (int mt = 0; mt < 4; ++mt)
#pragma unroll
            for (int nt = 0; nt < 2; ++nt)
#pragma unroll
                for (int h = 0; h < 2; ++h)
                    acc[mbase + mt][nbase + nt] = __builtin_amdgcn_mfma_f32_16x16x32_bf16(
                        af[mt][h], bf[nt][h], acc[mbase + mt][nbase + nt], 0, 0, 0);
        __builtin_amdgcn_s_setprio(0);
    };

    const int NITER = K >> 7;              // K=1024 -> 8 iters of 2 K-tiles
    for (int it = 0; it < NITER; ++it) {
        const int u = it * 2;
        // ================= K-tile u : buffer 0 =================
        // ph1 (q00): A m0-3 + B n0-1 (12 reads); stage A(u+1)h0 -> buf1
        read_a4(0, 0); read_b2(0, 0, b01);
        stage(Ab, &sA[1][0], u + 1, 0);
        LGKM8; BAR; LGKM0; mmq(0, 0, b01); BAR;
        // ph2 (q01): B n2-3 (4 reads); stage A(u+1)h1
        read_b2(0, 2, b23);
        stage(Ab, &sA[1][0], u + 1, 1);
        BAR; LGKM0; mmq(0, 2, b23); BAR;
        // ph3 (q11): A m4-7 (8 reads); buf0-B dead -> stage B(u+2)h0
        read_a4(0, 4);
        stage(Bb, &sB[0][0], u + 2, 0);
        BAR; LGKM0; mmq(4, 2, b23); BAR;
        // ph4 (q10): no reads; stage B(u+2)h1; counted wait: tile u+1 landed
        stage(Bb, &sB[0][0], u + 2, 1);
        BAR; mmq(4, 0, b01); BAR;
        VM4;
        // ================ K-tile u+1 : buffer 1 ================
        // ph5 (q00): buf0-A dead -> stage A(u+2)h0
        read_a4(1, 0); read_b2(1, 0, b01);
        stage(Ab, &sA[0][0], u + 2, 0);
        LGKM8; BAR; LGKM0; mmq(0, 0, b01); BAR;
        // ph6 (q01): stage A(u+2)h1
        read_b2(1, 2, b23);
        stage(Ab, &sA[0][0], u + 2, 1);
        BAR; LGKM0; mmq(0, 2, b23); BAR;
        // ph7 (q11): buf1-B dead -> stage B(u+3)h0
        read_a4(1, 4);
        stage(Bb, &sB[1][0], u + 3, 0);
        BAR; LGKM0; mmq(4, 2, b23); BAR;
        // ph8 (q10): stage B(u+3)h1; counted wait: tile u+2 landed
        stage(Bb, &sB[1][0], u + 3, 1);
        BAR; mmq(4, 0, b01); BAR;
        VM4;
        // (final iter stages tiles NT/NT+1: reads land in adjacent workspace
        //  regions -- in-bounds, written to dead LDS, never consumed)
    }

    // C/D layout 16x16x32 (verified m89/m91): col=lane&15, row=(lane>>4)*4+r
    const long mb = bm * 256 + wm * 128 + (fk << 2);
    const long nb = bn * 256 + wn * 64 + fr;
#pragma unroll
    for (int mt = 0; mt < 8; ++mt)
#pragma unroll
        for (int nt = 0; nt < 4; ++nt)
#pragma unroll
            for (int r = 0; r < 4; ++r)
                store_c(C, (mb + mt * 16 + r) * (long)N + nb + nt * 16, acc[mt][nt][r]);
}

// --------------------------- bf16 NT GEMM (GEMM2) --------------------------
template <int BM, int BN, typename CT>
__global__ __launch_bounds__(256) void gemm_bt(const unsigned short* __restrict__ A,
                                               const unsigned short* __restrict__ B,
                                               CT* __restrict__ C,
                                               int M, int N, int K) {
    constexpr int MI = BM / 64;
    constexpr int NJ = BN / 64;
    __shared__ __align__(16) unsigned short As[BM * 64];
    __shared__ __align__(16) unsigned short Bs[BN * 64];

    const int tid  = threadIdx.x;
    const int lane = tid & 63;
    const int wave = tid >> 6;
    const long bm  = blockIdx.y;
    const long bn  = blockIdx.x;
    const int wm   = (wave >> 1) * (BM / 2);
    const int wn   = (wave & 1) * (BN / 2);

    f32x16 acc[MI][NJ] = {};

    const unsigned short* Ab = A + bm * BM * (long)K;
    const unsigned short* Bb = B + bn * BN * (long)K;

    const int srow  = tid >> 3;
    const int sgcol = ((tid & 7) ^ (srow & 7)) << 3;

    for (int k0 = 0; k0 < K; k0 += 64) {
#pragma unroll
        for (int r = 0; r < BM / 32; ++r)
            __builtin_amdgcn_global_load_lds(
                (gbl_void*)(Ab + (long)(r * 32 + srow) * K + k0 + sgcol),
                (lds_void*)(As + (r * 256 + wave * 64) * 8), 16, 0, 0);
#pragma unroll
        for (int r = 0; r < BN / 32; ++r)
            __builtin_amdgcn_global_load_lds(
                (gbl_void*)(Bb + (long)(r * 32 + srow) * K + k0 + sgcol),
                (lds_void*)(Bs + (r * 256 + wave * 64) * 8), 16, 0, 0);
        __syncthreads();

        const int arow = lane & 31;
        const int kh   = lane >> 5;
#pragma unroll
        for (int kk = 0; kk < 4; ++kk) {
            const int c  = kk * 2 + kh;
            const int sw = (c ^ (lane & 7)) << 3;
            bf16x8 af[MI], bfr[NJ];
#pragma unroll
            for (int i = 0; i < MI; ++i)
                af[i] = *reinterpret_cast<const bf16x8*>(As + (wm + i * 32 + arow) * 64 + sw);
#pragma unroll
            for (int j = 0; j < NJ; ++j)
                bfr[j] = *reinterpret_cast<const bf16x8*>(Bs + (wn + j * 32 + arow) * 64 + sw);
#pragma unroll
            for (int i = 0; i < MI; ++i)
#pragma unroll
                for (int j = 0; j < NJ; ++j)
                    acc[i][j] = __builtin_amdgcn_mfma_f32_32x32x16_bf16(af[i], bfr[j], acc[i][j], 0, 0, 0);
        }
        __syncthreads();
    }

    const long mbase = bm * BM + wm + ((lane >> 5) << 2);
    const long nbase = bn * BN + wn + (lane & 31);
#pragma unroll
    for (int i = 0; i < MI; ++i)
#pragma unroll
        for (int j = 0; j < NJ; ++j)
#pragma unroll
            for (int r = 0; r < 16; ++r) {
                const long row = mbase + i * 32 + (r & 3) + 8 * (r >> 2);
                store_c(C, row * (long)N + nbase + j * 32, acc[i][j][r]);
            }
}

// ------------------- per-row head attention + scatter ----------------------
__global__ __launch_bounds__(256) void attn_rowlocal(const unsigned short* __restrict__ qkv,
                                                     unsigned short* __restrict__ out3) {
    __shared__ __align__(16) unsigned short rows[4 * 3072];  // 24 KB, swizzled
    __shared__ float attnS[4][16][17];                       // padded

    const int tid  = threadIdx.x;
    const int lane = tid & 63;
    const int wave = tid >> 6;
    const int m0   = blockIdx.x * 4;

    {   // cooperative load: LDS slot S gets global chunk (S&~7)|((S&7)^((S>>3)&7))
        const uint4* src = reinterpret_cast<const uint4*>(qkv + (long)m0 * 3072);
        uint4* dst = reinterpret_cast<uint4*>(rows);
#pragma unroll
        for (int c = 0; c < 6; ++c) {
            const int S  = c * 256 + tid;
            const int gs = (S & ~7) | ((S & 7) ^ ((S >> 3) & 7));
            dst[S] = src[gs];
        }
    }
    __syncthreads();

    const int m = m0 + wave;
    const int b = m >> 11;
    const int t = m & 2047;
    const unsigned short* rw = rows + wave * 3072;

    const int i  = lane & 15;
    const int j0 = (lane >> 4) << 2;
    float sc[4] = {0.f, 0.f, 0.f, 0.f};
#pragma unroll
    for (int c8 = 0; c8 < 8; ++c8) {
        uint4 qu = *reinterpret_cast<const uint4*>(rw + i * 64 + ((c8 ^ (i & 7)) << 3));
        float qf[8];
        unpack8(qu, qf);
#pragma unroll
        for (int jj = 0; jj < 4; ++jj) {
            const int vi = 16 + j0 + jj;
            uint4 ku = *reinterpret_cast<const uint4*>(rw + vi * 64 + ((c8 ^ (vi & 7)) << 3));
            float kf[8];
            unpack8(ku, kf);
#pragma unroll
            for (int d = 0; d < 8; ++d) sc[jj] += qf[d] * kf[d];
        }
    }
#pragma unroll
    for (int jj = 0; jj < 4; ++jj) sc[jj] *= 0.125f;

    float mx = fmaxf(fmaxf(sc[0], sc[1]), fmaxf(sc[2], sc[3]));
    mx = fmaxf(mx, __shfl_xor(mx, 16));
    mx = fmaxf(mx, __shfl_xor(mx, 32));
    float sum = 0.f;
#pragma unroll
    for (int jj = 0; jj < 4; ++jj) { sc[jj] = __expf(sc[jj] - mx); sum += sc[jj]; }
    sum += __shfl_xor(sum, 16);
    sum += __shfl_xor(sum, 32);
    const float inv = 1.0f / sum;
#pragma unroll
    for (int jj = 0; jj < 4; ++jj) attnS[wave][i][j0 + jj] = sc[jj] * inv;
    __syncthreads();

    const int oi = lane >> 2;
    const int s0 = (lane & 3) << 4;
    const int c0 = (lane & 3) << 1;
    float o[16];
#pragma unroll
    for (int ss = 0; ss < 16; ++ss) o[ss] = 0.f;
#pragma unroll
    for (int j = 0; j < 16; ++j) {
        const float a  = attnS[wave][oi][j];
        const int   vi = 32 + j;
        uint4 v0 = *reinterpret_cast<const uint4*>(rw + vi * 64 + (((c0)     ^ (vi & 7)) << 3));
        uint4 v1 = *reinterpret_cast<const uint4*>(rw + vi * 64 + (((c0 + 1) ^ (vi & 7)) << 3));
        float vf[16];
        unpack8(v0, vf);
        unpack8(v1, vf + 8);
#pragma unroll
        for (int ss = 0; ss < 16; ++ss) o[ss] += a * vf[ss];
    }

    uint4 r0, r1;
    r0.x = pack2(o[0],  o[1]);  r0.y = pack2(o[2],  o[3]);
    r0.z = pack2(o[4],  o[5]);  r0.w = pack2(o[6],  o[7]);
    r1.x = pack2(o[8],  o[9]);  r1.y = pack2(o[10], o[11]);
    r1.z = pack2(o[12], o[13]); r1.w = pack2(o[14], o[15]);

    const long base = (long)b * (2048 * 1024)
                    + (long)(oi * 128 + (t >> 4)) * 1024
                    + 64 * (t & 15) + s0;
    *reinterpret_cast<uint4*>(out3 + base)     = r0;
    *reinterpret_cast<uint4*>(out3 + base + 8) = r1;
}

// ------------------------------- launcher ----------------------------------
extern "C" void kernel_launch(void* const* d_in, const int* in_sizes, int n_in,
                              void* d_out, int out_size, void* d_ws, size_t ws_size,
                              hipStream_t stream) {
    const float* x     = (const float*)d_in[0];   // (4,2048,1024)
    const float* Wqkv  = (const float*)d_in[1];   // (3072,1024)
    const float* Wproj = (const float*)d_in[2];   // (1024,1024)
    float* out = (float*)d_out;                   // (4,2048,1024) fp32

    char* ws = (char*)d_ws;
    unsigned short* xb     = (unsigned short*)(ws);               // 16.0 MiB
    unsigned short* wqkvb  = (unsigned short*)(ws + 16777216);    //  6.0 MiB
    unsigned short* wprojb = (unsigned short*)(ws + 23068672);    //  2.0 MiB
    unsigned short* qkvb   = (unsigned short*)(ws + 25165824);    // 48.0 MiB
    unsigned short* out3b  = (unsigned short*)(ws + 75497472);    // 16.0 MiB

    // all three fp32->bf16 casts in one dispatch (3,145,728 float4s)
    cvt_all<<<dim3(12288), dim3(256), 0, stream>>>(x, Wqkv, Wproj, xb, wqkvb, wprojb);

    // qkv = x @ Wqkv^T : M=8192, N=3072, K=1024  (256x256 8-phase, 384 blocks)
    gemm256p<unsigned short><<<dim3(384), dim3(512), 0, stream>>>(
        xb, wqkvb, qkvb, 8192, 3072, 1024, 12);

    attn_rowlocal<<<dim3(2048), dim3(256), 0, stream>>>(qkvb, out3b);

    // out = out3 @ Wproj^T : M=8192, N=1024, K=1024  (64x128 tiles, 4 blk/CU)
    gemm_bt<64, 128, float><<<dim3(8, 128), dim3(256), 0, stream>>>(
        out3b, wprojb, out, 8192, 1024, 1024);
}